// Round 10
// baseline (169.897 us; speedup 1.0000x reference)
//
#include <hip/hip_runtime.h>
#include <stdint.h>

typedef short bf16x8 __attribute__((ext_vector_type(8)));
typedef unsigned short u16x8 __attribute__((ext_vector_type(8)));
typedef float f32x4 __attribute__((ext_vector_type(4)));
typedef float f32x8 __attribute__((ext_vector_type(8)));

constexpr int BT_TOT = 768;   // B*T
constexpr int M_N    = 512;   // nodes (contraction length for stage 1)
constexpr int DD     = 64;    // Din = Dout
constexpr int WROW   = 72;    // W' row stride in route_mm (144B, bank step 4)

// d_out dual-use layout (256B per output row, row = bt*512 + m):
//   low  128B: H[bt][m][d] bf16 (written by gconv, read by route_mm)
//   high 128B: xT[bt][d][n] bf16 (written by prep_x, read by gconv)
//     element (bt,d,n) at byte (bt*512 + 8*d + (n>>6))*256 + 128 + (n&63)*2
// route_mm finally overwrites every row with f32 out. Stream-serial => race-free.

__device__ __forceinline__ unsigned short f2bf(float f) {
  unsigned u = __builtin_bit_cast(unsigned, f);
  u += 0x7fffu + ((u >> 16) & 1u);          // RNE
  return (unsigned short)(u >> 16);
}
__device__ __forceinline__ unsigned pk2(float a, float b) {
  return (unsigned)f2bf(a) | ((unsigned)f2bf(b) << 16);
}

// ---------------- prep: adj f32 -> bf16 (once) ----------------
__global__ __launch_bounds__(256)
void prep_adj(const float* __restrict__ adjg, unsigned short* __restrict__ wsadj) {
  int i = (blockIdx.x * 256 + threadIdx.x) * 8;
  f32x8 a = *(const f32x8*)(adjg + i);
  u16x8 r;
  #pragma unroll
  for (int j = 0; j < 8; ++j) r[j] = f2bf(a[j]);
  *(u16x8*)(wsadj + i) = r;
}

// ---------------- prep_x: x f32 [bt][n][d] -> xT bf16 [bt][d][n] ----------------
// WG = (bt, half): 4 chunks of 64 n. Verified v8 coalesced load + v9 butterfly
// + swizzled LDS write; readout is conflict-free (pos = o ^ g3d per 8-lane group)
// and writes 128B-contiguous high-half segments.
__global__ __launch_bounds__(256, 4)
void prep_x(const float* __restrict__ xg, char* __restrict__ xout) {
  __shared__ __align__(16) char lds[2][8192];

  const int wid  = blockIdx.x;          // 0..1535
  const int bt   = wid >> 1;
  const int half = wid & 1;
  const int tid  = threadIdx.x;
  const int lane = tid & 63;
  const int wv   = tid >> 6;
  const int gg   = lane >> 4;
  const int c4   = lane & 15;

  const float* xb = xg + (size_t)bt * (M_N * DD);

  f32x4 xv[4];
  auto load_c = [&](int c) {
    #pragma unroll
    for (int s = 0; s < 4; ++s)
      xv[s] = *(const f32x4*)(xb + (size_t)(c*64 + s*16 + wv*4 + gg) * DD + c4*4);
  };

  load_c(half*4);
  #pragma unroll
  for (int cc = 0; cc < 4; ++cc) {
    const int c = half*4 + cc;
    char* xt = &lds[cc & 1][0];
    { // butterfly transpose-pack (verified): lane ends with d = c4*4+gg
      const int d   = c4*4 + gg;
      const int g3d = (d & 7) ^ ((d >> 3) & 7);
      #pragma unroll
      for (int s = 0; s < 4; ++s) {
        const int n4 = s*4 + wv;
        unsigned u0 = pk2(xv[s].x, xv[s].y);
        unsigned u1 = pk2(xv[s].z, xv[s].w);
        unsigned t0 = __shfl_xor(u0, 32);
        unsigned t1 = __shfl_xor(u1, 32);
        unsigned v0 = (gg & 2) ? t1 : u0;
        unsigned v1 = (gg & 2) ? u1 : t0;
        unsigned s0 = __shfl_xor(v0, 16);
        unsigned s1 = __shfl_xor(v1, 16);
        unsigned F0 = (gg & 1) ? ((s0 >> 16) | (v0 & 0xFFFF0000u))
                               : ((v0 & 0xFFFFu) | (s0 << 16));
        unsigned F1 = (gg & 1) ? ((s1 >> 16) | (v1 & 0xFFFF0000u))
                               : ((v1 & 0xFFFFu) | (s1 << 16));
        uint2 o2; o2.x = F0; o2.y = F1;
        *(uint2*)(xt + d*128 + (((n4 >> 1) ^ g3d) * 16) + (n4 & 1)*8) = o2;
      }
    }
    if (cc < 3) load_c(c + 1);
    __syncthreads();
    // readout: 2 granules/thread; LDS pos p = o ^ g3d holds n-granule o
    #pragma unroll
    for (int h = 0; h < 2; ++h) {
      const int g   = tid + h*256;       // 0..511
      const int d   = g >> 3;            // 0..63
      const int o   = g & 7;             // 16B n-granule (n = o*8..o*8+7)
      const int g3d = (d & 7) ^ ((d >> 3) & 7);
      u16x8 val = *(const u16x8*)(xt + d*128 + ((o ^ g3d) * 16));
      *(u16x8*)(xout + ((size_t)(bt*512 + 8*d + c)) * 256 + 128 + o*16) = val;
    }
    // next write targets the other buffer; this buffer's reads are in regs
    // before the next __syncthreads -> 1 barrier per chunk is sufficient
  }
}

// ---------------- Kernel A v10: barrier-free, LDS-free GEMM ----------------
// H[bt][m][d] = sum_n adj[m][n]*x[bt][n][d]. WG = 2 bt x 128 m, 4 waves;
// wave = 32 m x 64 d x 2 bt. Both operands k-contiguous bf16 from global:
// afr from adj (L2-resident), bfx from xT (high halves of d_out). 16 k-slices,
// 16 MFMA + 10 b128 loads per slice, no syncs anywhere -> compiler+TLP pipeline.
template<bool WS>
__global__ __launch_bounds__(256, 3)
void gconv_h(const float* __restrict__ adjf,           // [512][512] f32 (fallback)
             const unsigned short* __restrict__ adjb,  // [512][512] bf16 (ws path)
             char* __restrict__ dio)                   // d_out bytes
{
  const int wid  = blockIdx.x;          // 0..1535, bijective XCD swizzle
  const int xcd  = wid & 7;
  const int slot = wid >> 3;            // 0..191
  const int mb   = slot & 3;            // 4 consecutive slots share bt-pair
  const int btp  = (slot >> 2) * 8 + xcd;   // 0..383
  const int bt0  = btp * 2;

  const int tid  = threadIdx.x;
  const int lane = tid & 63;
  const int wv   = tid >> 6;
  const int l15  = lane & 15;
  const int gg   = lane >> 4;
  const int mrow = mb*128 + wv*32;

  f32x4 acc[2][2][4];                   // [bb][mt][dt]
  #pragma unroll
  for (int bb = 0; bb < 2; ++bb)
    #pragma unroll
    for (int mt = 0; mt < 2; ++mt)
      #pragma unroll
      for (int dt = 0; dt < 4; ++dt) acc[bb][mt][dt] = f32x4{0.f,0.f,0.f,0.f};

  #pragma unroll 4
  for (int kl = 0; kl < 16; ++kl) {
    bf16x8 afr[2];
    #pragma unroll
    for (int mt = 0; mt < 2; ++mt) {
      const int m = mrow + mt*16 + l15;
      if (WS) {
        afr[mt] = __builtin_bit_cast(bf16x8,
            *(const u16x8*)(adjb + (size_t)m*M_N + kl*32 + gg*8));
      } else {
        f32x8 a = *(const f32x8*)(adjf + (size_t)m*M_N + kl*32 + gg*8);
        u16x8 r;
        #pragma unroll
        for (int j = 0; j < 8; ++j) r[j] = f2bf(a[j]);
        afr[mt] = __builtin_bit_cast(bf16x8, r);
      }
    }
    bf16x8 bfx[2][4];
    #pragma unroll
    for (int bb = 0; bb < 2; ++bb)
      #pragma unroll
      for (int dt = 0; dt < 4; ++dt) {
        const int d = dt*16 + l15;
        bfx[bb][dt] = __builtin_bit_cast(bf16x8, *(const u16x8*)(dio
            + ((size_t)((bt0+bb)*512 + 8*d + (kl >> 1))) * 256
            + 128 + (kl & 1)*64 + gg*16));
      }
    #pragma unroll
    for (int bb = 0; bb < 2; ++bb)
      #pragma unroll
      for (int mt = 0; mt < 2; ++mt)
        #pragma unroll
        for (int dt = 0; dt < 4; ++dt)
          acc[bb][mt][dt] = __builtin_amdgcn_mfma_f32_16x16x32_bf16(
              afr[mt], bfx[bb][dt], acc[bb][mt][dt], 0,0,0);
  }

  // epilogue: H store (bf16, low half of each d_out row) — verified pattern
  #pragma unroll
  for (int bb = 0; bb < 2; ++bb)
    #pragma unroll
    for (int mt = 0; mt < 2; ++mt)
      #pragma unroll
      for (int dt = 0; dt < 4; ++dt)
        #pragma unroll
        for (int r = 0; r < 4; ++r) {
          const int m = mrow + mt*16 + gg*4 + r;   // C row = (lane>>4)*4 + reg
          const int d = dt*16 + l15;
          *(unsigned short*)(dio + ((size_t)(bt0+bb)*M_N + m)*256 + 2*d)
              = f2bf(acc[bb][mt][dt][r]);
        }
}

// ---------------- Kernel B (unchanged, verified) ----------------
__global__ __launch_bounds__(256, 4)
void route_mm(const char* __restrict__ hin,
              const float* __restrict__ wgt,
              const float* __restrict__ bias,
              float* __restrict__ outg)
{
  __shared__ unsigned short wb[128 * WROW];

  const int m0    = blockIdx.x * 2;
  const int btblk = blockIdx.y * 64;
  const int tid   = threadIdx.x;
  const int lane  = tid & 63;
  const int wv    = tid >> 6;
  const int l15   = lane & 15;
  const int gg    = lane >> 4;
  const int dp    = tid & 31;
  const int lo    = tid >> 5;

  { const float* q = wgt + ((size_t)m0*64 + dp*2)*64 + lo*8;
    f32x8 w0 = *(const f32x8*)q;          f32x8 w1 = *(const f32x8*)(q+64);
    f32x8 w2 = *(const f32x8*)(q+4096);   f32x8 w3 = *(const f32x8*)(q+4160);
    #pragma unroll
    for (int e = 0; e < 8; ++e) {
      int lrow = lo*8 + e;
      unsigned v0 = pk2(w0[e], w1[e]);
      unsigned v1 = pk2(w2[e], w3[e]);
      *(unsigned*)(wb + lrow*WROW + dp*2)        = v0;
      *(unsigned*)(wb + (64 + lrow)*WROW + dp*2) = v1;
    }
  }
  __syncthreads();

  const int btw0 = btblk + wv*16;

  #pragma unroll
  for (int mm = 0; mm < 2; ++mm) {
    const int m = m0 + mm;
    bf16x8 afr[2];
    #pragma unroll
    for (int ks = 0; ks < 2; ++ks) {
      const char* hp = hin + ((size_t)(btw0 + l15)*M_N + m)*256 + ks*64 + gg*16;
      afr[ks] = __builtin_bit_cast(bf16x8, *(const u16x8*)hp);
    }
    f32x4 acc[4];
    #pragma unroll
    for (int lt = 0; lt < 4; ++lt) acc[lt] = f32x4{0.f,0.f,0.f,0.f};
    #pragma unroll
    for (int lt = 0; lt < 4; ++lt)
      #pragma unroll
      for (int ks = 0; ks < 2; ++ks) {
        bf16x8 bfr = __builtin_bit_cast(bf16x8,
            *(const u16x8*)(wb + (mm*64 + lt*16 + l15)*WROW + ks*32 + gg*8));
        acc[lt] = __builtin_amdgcn_mfma_f32_16x16x32_bf16(afr[ks], bfr, acc[lt], 0,0,0);
      }
    #pragma unroll
    for (int lt = 0; lt < 4; ++lt) {
      float bv = bias[m*64 + lt*16 + l15];
      #pragma unroll
      for (int r = 0; r < 4; ++r) {
        size_t row = (size_t)(btw0 + gg*4 + r)*M_N + m;
        outg[row*64 + lt*16 + l15] = acc[lt][r] + bv;
      }
    }
  }
}

extern "C" void kernel_launch(void* const* d_in, const int* in_sizes, int n_in,
                              void* d_out, int out_size, void* d_ws, size_t ws_size,
                              hipStream_t stream) {
  const float* xg   = (const float*)d_in[0];
  const float* adjg = (const float*)d_in[1];
  const float* wgt  = (const float*)d_in[2];
  const float* bg   = (const float*)d_in[3];

  prep_x<<<dim3(BT_TOT * 2), dim3(256), 0, stream>>>(xg, (char*)d_out);

  const size_t adj_bf_bytes = (size_t)M_N * M_N * 2;   // 512 KB
  if (ws_size >= adj_bf_bytes) {
    unsigned short* wsadj = (unsigned short*)d_ws;
    prep_adj<<<dim3(M_N * M_N / (256 * 8)), dim3(256), 0, stream>>>(adjg, wsadj);
    gconv_h<true><<<dim3(1536), dim3(256), 0, stream>>>(adjg, wsadj, (char*)d_out);
  } else {
    gconv_h<false><<<dim3(1536), dim3(256), 0, stream>>>(adjg, nullptr, (char*)d_out);
  }
  route_mm<<<dim3(M_N/2, BT_TOT/64), dim3(256), 0, stream>>>(
      (const char*)d_out, wgt, bg, (float*)d_out);
}

// Round 11
// 97.895 us; speedup vs baseline: 1.7355x; 1.7355x over previous
//
#include <hip/hip_runtime.h>
#include <stdint.h>

typedef short bf16x8 __attribute__((ext_vector_type(8)));
typedef unsigned short u16x8 __attribute__((ext_vector_type(8)));
typedef float f32x4 __attribute__((ext_vector_type(4)));
typedef float f32x8 __attribute__((ext_vector_type(8)));

constexpr int BT_TOT = 768;   // B*T
constexpr int M_N    = 512;   // nodes
constexpr int DD     = 64;    // Din = Dout
constexpr int WROW   = 72;    // W' row stride in route_mm

// fast-path d_ws layout:
//   [0, 512K):        adj bf16, MFMA-fragment order: granule(m, ko) at
//                     (((m>>4)*16 + (ko>>2))*64 + (ko&3)*16 + (m&15))*16B
//   [512K, 512K+48M): xtf bf16 per bt (64KB): granule(d, o) at
//                     bt*64K + (((n>>5)*4 + (d>>4))*64 + ((n>>3)&3)*16 + (d&15))*16B
// -> in gconv, BOTH operand loads are base + lane*16 (contiguous 1KB/wave).
constexpr size_t ADJ_FRAG_B = (size_t)M_N * M_N * 2;          // 512 KB
constexpr size_t XTF_B      = (size_t)BT_TOT * M_N * DD * 2;  // 48 MB

__device__ __forceinline__ unsigned short f2bf(float f) {
  unsigned u = __builtin_bit_cast(unsigned, f);
  u += 0x7fffu + ((u >> 16) & 1u);          // RNE
  return (unsigned short)(u >> 16);
}
__device__ __forceinline__ unsigned pk2(float a, float b) {
  return (unsigned)f2bf(a) | ((unsigned)f2bf(b) << 16);
}

// ================= FAST PATH =================

// adj f32 -> bf16 fragment layout (512 KB, once per call)
__global__ __launch_bounds__(256)
void prep_adj_frag(const float* __restrict__ adjg, unsigned short* __restrict__ wsadj) {
  int t  = blockIdx.x * 256 + threadIdx.x;   // granule id = m*64 + ko (32768 total)
  int m  = t >> 6, ko = t & 63;
  f32x8 a = *(const f32x8*)(adjg + (size_t)m * M_N + ko * 8);
  u16x8 r;
  #pragma unroll
  for (int j = 0; j < 8; ++j) r[j] = f2bf(a[j]);
  size_t g = (size_t)((m >> 4) * 16 + (ko >> 2)) * 64 + (ko & 3) * 16 + (m & 15);
  *(u16x8*)(wsadj + g * 8) = r;
}

// x f32 [bt][n][d] -> xtf bf16 fragment layout. NO LDS, NO barriers:
// coalesced loads + verified in-register butterfly; each lane accumulates
// 2 complete granules (8 n for its d) in registers, stores them directly.
__global__ __launch_bounds__(256)
void prep_x_fast(const float* __restrict__ xg, unsigned short* __restrict__ xtf) {
  const int wid = blockIdx.x;          // 0..3071
  const int bt  = wid >> 2, q = wid & 3;
  const int tid = threadIdx.x, lane = tid & 63, w = tid >> 6;
  const int gg  = lane >> 4, c4 = lane & 15;

  const float* xb = xg + (size_t)bt * (M_N * DD);
  unsigned short* xo = xtf + (size_t)bt * 32768;   // elems

  #pragma unroll
  for (int cc = 0; cc < 2; ++cc) {
    const int c = q * 2 + cc;          // chunk of 64 n
    unsigned r0[4], r1[4];             // granules o = w*2, w*2+1 (4 dwords each)
    #pragma unroll
    for (int s2 = 0; s2 < 2; ++s2) {   // granule half-select
      #pragma unroll
      for (int sp = 0; sp < 2; ++sp) { // sweep s' = s2*2+sp
        const int n = c*64 + w*16 + (s2*2 + sp)*4 + gg;    // coalesced 1KB/wave
        f32x4 xv = *(const f32x4*)(xb + (size_t)n * DD + c4*4);
        unsigned u0 = pk2(xv.x, xv.y), u1 = pk2(xv.z, xv.w);
        unsigned t0 = __shfl_xor(u0, 32), t1 = __shfl_xor(u1, 32);
        unsigned v0 = (gg & 2) ? t1 : u0, v1 = (gg & 2) ? u1 : t0;
        unsigned s0 = __shfl_xor(v0, 16), s1 = __shfl_xor(v1, 16);
        unsigned F0 = (gg & 1) ? ((s0 >> 16) | (v0 & 0xFFFF0000u))
                               : ((v0 & 0xFFFFu) | (s0 << 16));
        unsigned F1 = (gg & 1) ? ((s1 >> 16) | (v1 & 0xFFFF0000u))
                               : ((v1 & 0xFFFFu) | (s1 << 16));
        if (s2 == 0) { r0[sp*2] = F0; r0[sp*2+1] = F1; }
        else         { r1[sp*2] = F0; r1[sp*2+1] = F1; }
      }
    }
    const int d = c4*4 + gg, dt = d >> 4, l15p = d & 15;
    #pragma unroll
    for (int h = 0; h < 2; ++h) {      // store granule (d, o = w*2+h)
      const int o  = w*2 + h;
      const int kl = c*2 + (o >> 2), ggp = o & 3;
      uint4 val;
      if (h == 0) { val.x=r0[0]; val.y=r0[1]; val.z=r0[2]; val.w=r0[3]; }
      else        { val.x=r1[0]; val.y=r1[1]; val.z=r1[2]; val.w=r1[3]; }
      *(uint4*)(xo + ((size_t)(kl*4 + dt)*64 + ggp*16 + l15p) * 8) = val;
    }
  }
}

// H = adj @ x : all loads contiguous (base + lane*16), no staging, no barriers
// until the epilogue LDS repack. WG = 2 bt x 128 m, 4 waves.
__global__ __launch_bounds__(256, 3)
void gconv_fast(const unsigned short* __restrict__ adjF,
                const unsigned short* __restrict__ xtf,
                char* __restrict__ dio) {
  __shared__ unsigned short Hb[256 * 72];        // [bb*128+m][72], 36864 B

  const int wid  = blockIdx.x;        // 0..1535, bijective XCD swizzle
  const int xcd  = wid & 7, slot = wid >> 3;
  const int mb   = slot & 3;
  const int bt0  = ((slot >> 2) * 8 + xcd) * 2;

  const int tid  = threadIdx.x, lane = tid & 63, wv = tid >> 6;
  const int l15  = lane & 15, gg = lane >> 4;

  const unsigned short* xo0 = xtf + (size_t)bt0 * 32768;
  const unsigned short* xo1 = xtf + (size_t)(bt0 + 1) * 32768;

  f32x4 acc[2][2][4];
  #pragma unroll
  for (int bb = 0; bb < 2; ++bb)
    #pragma unroll
    for (int mt = 0; mt < 2; ++mt)
      #pragma unroll
      for (int dt = 0; dt < 4; ++dt) acc[bb][mt][dt] = f32x4{0.f,0.f,0.f,0.f};

  #pragma unroll 4
  for (int kl = 0; kl < 16; ++kl) {
    bf16x8 afr[2];
    #pragma unroll
    for (int mt = 0; mt < 2; ++mt)
      afr[mt] = __builtin_bit_cast(bf16x8, *(const u16x8*)(adjF
          + ((size_t)((mb*8 + wv*2 + mt)*16 + kl)*64 + lane) * 8));
    bf16x8 bfx[2][4];
    #pragma unroll
    for (int dt = 0; dt < 4; ++dt) {
      bfx[0][dt] = __builtin_bit_cast(bf16x8,
          *(const u16x8*)(xo0 + ((size_t)(kl*4 + dt)*64 + lane) * 8));
      bfx[1][dt] = __builtin_bit_cast(bf16x8,
          *(const u16x8*)(xo1 + ((size_t)(kl*4 + dt)*64 + lane) * 8));
    }
    #pragma unroll
    for (int bb = 0; bb < 2; ++bb)
      #pragma unroll
      for (int mt = 0; mt < 2; ++mt)
        #pragma unroll
        for (int dt = 0; dt < 4; ++dt)
          acc[bb][mt][dt] = __builtin_amdgcn_mfma_f32_16x16x32_bf16(
              afr[mt], bfx[bb][dt], acc[bb][mt][dt], 0,0,0);
  }

  // epilogue: acc -> LDS (verified C-layout) -> dense 128B-segment stores
  #pragma unroll
  for (int bb = 0; bb < 2; ++bb)
    #pragma unroll
    for (int mt = 0; mt < 2; ++mt)
      #pragma unroll
      for (int dt = 0; dt < 4; ++dt)
        #pragma unroll
        for (int r = 0; r < 4; ++r)
          Hb[(bb*128 + wv*32 + mt*16 + gg*4 + r)*72 + dt*16 + l15]
              = f2bf(acc[bb][mt][dt][r]);
  __syncthreads();
  #pragma unroll
  for (int j = 0; j < 8; ++j) {
    const int rl = j*32 + (tid >> 3);           // 0..255 = bb*128 + mloc
    u16x8 v = *(const u16x8*)(&Hb[rl*72 + (tid & 7)*8]);
    const int bb = rl >> 7, mloc = rl & 127;
    *(u16x8*)(dio + ((size_t)(bt0 + bb)*M_N + mb*128 + mloc)*256 + (tid & 7)*16) = v;
  }
}

// ================= FALLBACK PATH (v10, verified @170us) =================

__global__ __launch_bounds__(256)
void prep_adj(const float* __restrict__ adjg, unsigned short* __restrict__ wsadj) {
  int i = (blockIdx.x * 256 + threadIdx.x) * 8;
  f32x8 a = *(const f32x8*)(adjg + i);
  u16x8 r;
  #pragma unroll
  for (int j = 0; j < 8; ++j) r[j] = f2bf(a[j]);
  *(u16x8*)(wsadj + i) = r;
}

__global__ __launch_bounds__(256, 4)
void prep_x_fb(const float* __restrict__ xg, char* __restrict__ xout) {
  __shared__ __align__(16) char lds[2][8192];
  const int wid  = blockIdx.x;
  const int bt   = wid >> 1, half = wid & 1;
  const int tid  = threadIdx.x, lane = tid & 63, wv = tid >> 6;
  const int gg   = lane >> 4, c4 = lane & 15;
  const float* xb = xg + (size_t)bt * (M_N * DD);
  f32x4 xv[4];
  auto load_c = [&](int c) {
    #pragma unroll
    for (int s = 0; s < 4; ++s)
      xv[s] = *(const f32x4*)(xb + (size_t)(c*64 + s*16 + wv*4 + gg) * DD + c4*4);
  };
  load_c(half*4);
  #pragma unroll
  for (int cc = 0; cc < 4; ++cc) {
    const int c = half*4 + cc;
    char* xt = &lds[cc & 1][0];
    { const int d = c4*4 + gg, g3d = (d & 7) ^ ((d >> 3) & 7);
      #pragma unroll
      for (int s = 0; s < 4; ++s) {
        const int n4 = s*4 + wv;
        unsigned u0 = pk2(xv[s].x, xv[s].y), u1 = pk2(xv[s].z, xv[s].w);
        unsigned t0 = __shfl_xor(u0, 32), t1 = __shfl_xor(u1, 32);
        unsigned v0 = (gg & 2) ? t1 : u0, v1 = (gg & 2) ? u1 : t0;
        unsigned s0 = __shfl_xor(v0, 16), s1 = __shfl_xor(v1, 16);
        unsigned F0 = (gg & 1) ? ((s0 >> 16) | (v0 & 0xFFFF0000u))
                               : ((v0 & 0xFFFFu) | (s0 << 16));
        unsigned F1 = (gg & 1) ? ((s1 >> 16) | (v1 & 0xFFFF0000u))
                               : ((v1 & 0xFFFFu) | (s1 << 16));
        uint2 o2; o2.x = F0; o2.y = F1;
        *(uint2*)(xt + d*128 + (((n4 >> 1) ^ g3d) * 16) + (n4 & 1)*8) = o2;
      }
    }
    if (cc < 3) load_c(c + 1);
    __syncthreads();
    #pragma unroll
    for (int h = 0; h < 2; ++h) {
      const int g = tid + h*256, d = g >> 3, o = g & 7;
      const int g3d = (d & 7) ^ ((d >> 3) & 7);
      u16x8 val = *(const u16x8*)(xt + d*128 + ((o ^ g3d) * 16));
      *(u16x8*)(xout + ((size_t)(bt*512 + 8*d + c)) * 256 + 128 + o*16) = val;
    }
  }
}

template<bool WS>
__global__ __launch_bounds__(256, 3)
void gconv_fb(const float* __restrict__ adjf,
              const unsigned short* __restrict__ adjb,
              char* __restrict__ dio) {
  const int wid  = blockIdx.x;
  const int xcd  = wid & 7, slot = wid >> 3;
  const int mb   = slot & 3;
  const int bt0  = ((slot >> 2) * 8 + xcd) * 2;
  const int tid  = threadIdx.x, lane = tid & 63, wv = tid >> 6;
  const int l15  = lane & 15, gg = lane >> 4;
  const int mrow = mb*128 + wv*32;
  f32x4 acc[2][2][4];
  #pragma unroll
  for (int bb = 0; bb < 2; ++bb)
    #pragma unroll
    for (int mt = 0; mt < 2; ++mt)
      #pragma unroll
      for (int dt = 0; dt < 4; ++dt) acc[bb][mt][dt] = f32x4{0.f,0.f,0.f,0.f};
  #pragma unroll 4
  for (int kl = 0; kl < 16; ++kl) {
    bf16x8 afr[2];
    #pragma unroll
    for (int mt = 0; mt < 2; ++mt) {
      const int m = mrow + mt*16 + l15;
      if (WS) {
        afr[mt] = __builtin_bit_cast(bf16x8,
            *(const u16x8*)(adjb + (size_t)m*M_N + kl*32 + gg*8));
      } else {
        f32x8 a = *(const f32x8*)(adjf + (size_t)m*M_N + kl*32 + gg*8);
        u16x8 r;
        #pragma unroll
        for (int j = 0; j < 8; ++j) r[j] = f2bf(a[j]);
        afr[mt] = __builtin_bit_cast(bf16x8, r);
      }
    }
    bf16x8 bfx[2][4];
    #pragma unroll
    for (int bb = 0; bb < 2; ++bb)
      #pragma unroll
      for (int dt = 0; dt < 4; ++dt) {
        const int d = dt*16 + l15;
        bfx[bb][dt] = __builtin_bit_cast(bf16x8, *(const u16x8*)(dio
            + ((size_t)((bt0+bb)*512 + 8*d + (kl >> 1))) * 256
            + 128 + (kl & 1)*64 + gg*16));
      }
    #pragma unroll
    for (int bb = 0; bb < 2; ++bb)
      #pragma unroll
      for (int mt = 0; mt < 2; ++mt)
        #pragma unroll
        for (int dt = 0; dt < 4; ++dt)
          acc[bb][mt][dt] = __builtin_amdgcn_mfma_f32_16x16x32_bf16(
              afr[mt], bfx[bb][dt], acc[bb][mt][dt], 0,0,0);
  }
  #pragma unroll
  for (int bb = 0; bb < 2; ++bb)
    #pragma unroll
    for (int mt = 0; mt < 2; ++mt)
      #pragma unroll
      for (int dt = 0; dt < 4; ++dt)
        #pragma unroll
        for (int r = 0; r < 4; ++r) {
          const int m = mrow + mt*16 + gg*4 + r, d = dt*16 + l15;
          *(unsigned short*)(dio + ((size_t)(bt0+bb)*M_N + m)*256 + 2*d)
              = f2bf(acc[bb][mt][dt][r]);
        }
}

// ---------------- Kernel B (unchanged, verified) ----------------
__global__ __launch_bounds__(256, 4)
void route_mm(const char* __restrict__ hin,
              const float* __restrict__ wgt,
              const float* __restrict__ bias,
              float* __restrict__ outg) {
  __shared__ unsigned short wb[128 * WROW];
  const int m0    = blockIdx.x * 2;
  const int btblk = blockIdx.y * 64;
  const int tid   = threadIdx.x, lane = tid & 63, wv = tid >> 6;
  const int l15   = lane & 15, gg = lane >> 4;
  const int dp    = tid & 31, lo = tid >> 5;
  { const float* q = wgt + ((size_t)m0*64 + dp*2)*64 + lo*8;
    f32x8 w0 = *(const f32x8*)q;          f32x8 w1 = *(const f32x8*)(q+64);
    f32x8 w2 = *(const f32x8*)(q+4096);   f32x8 w3 = *(const f32x8*)(q+4160);
    #pragma unroll
    for (int e = 0; e < 8; ++e) {
      int lrow = lo*8 + e;
      *(unsigned*)(wb + lrow*WROW + dp*2)        = pk2(w0[e], w1[e]);
      *(unsigned*)(wb + (64 + lrow)*WROW + dp*2) = pk2(w2[e], w3[e]);
    }
  }
  __syncthreads();
  const int btw0 = btblk + wv*16;
  #pragma unroll
  for (int mm = 0; mm < 2; ++mm) {
    const int m = m0 + mm;
    bf16x8 afr[2];
    #pragma unroll
    for (int ks = 0; ks < 2; ++ks) {
      const char* hp = hin + ((size_t)(btw0 + l15)*M_N + m)*256 + ks*64 + gg*16;
      afr[ks] = __builtin_bit_cast(bf16x8, *(const u16x8*)hp);
    }
    f32x4 acc[4];
    #pragma unroll
    for (int lt = 0; lt < 4; ++lt) acc[lt] = f32x4{0.f,0.f,0.f,0.f};
    #pragma unroll
    for (int lt = 0; lt < 4; ++lt)
      #pragma unroll
      for (int ks = 0; ks < 2; ++ks) {
        bf16x8 bfr = __builtin_bit_cast(bf16x8,
            *(const u16x8*)(wb + (mm*64 + lt*16 + l15)*WROW + ks*32 + gg*8));
        acc[lt] = __builtin_amdgcn_mfma_f32_16x16x32_bf16(afr[ks], bfr, acc[lt], 0,0,0);
      }
    #pragma unroll
    for (int lt = 0; lt < 4; ++lt) {
      float bv = bias[m*64 + lt*16 + l15];
      #pragma unroll
      for (int r = 0; r < 4; ++r) {
        size_t row = (size_t)(btw0 + gg*4 + r)*M_N + m;
        outg[row*64 + lt*16 + l15] = acc[lt][r] + bv;
      }
    }
  }
}

extern "C" void kernel_launch(void* const* d_in, const int* in_sizes, int n_in,
                              void* d_out, int out_size, void* d_ws, size_t ws_size,
                              hipStream_t stream) {
  const float* xg   = (const float*)d_in[0];
  const float* adjg = (const float*)d_in[1];
  const float* wgt  = (const float*)d_in[2];
  const float* bg   = (const float*)d_in[3];

  if (ws_size >= ADJ_FRAG_B + XTF_B) {
    unsigned short* adjF = (unsigned short*)d_ws;
    unsigned short* xtf  = (unsigned short*)((char*)d_ws + ADJ_FRAG_B);
    prep_adj_frag<<<dim3(128), dim3(256), 0, stream>>>(adjg, adjF);
    prep_x_fast<<<dim3(BT_TOT * 4), dim3(256), 0, stream>>>(xg, xtf);
    gconv_fast<<<dim3(1536), dim3(256), 0, stream>>>(adjF, xtf, (char*)d_out);
  } else {
    prep_x_fb<<<dim3(BT_TOT * 2), dim3(256), 0, stream>>>(xg, (char*)d_out);
    if (ws_size >= ADJ_FRAG_B) {
      unsigned short* wsadj = (unsigned short*)d_ws;
      prep_adj<<<dim3(M_N * M_N / (256 * 8)), dim3(256), 0, stream>>>(adjg, wsadj);
      gconv_fb<true><<<dim3(1536), dim3(256), 0, stream>>>(adjg, wsadj, (char*)d_out);
    } else {
      gconv_fb<false><<<dim3(1536), dim3(256), 0, stream>>>(adjg, nullptr, (char*)d_out);
    }
  }
  route_mm<<<dim3(M_N/2, BT_TOT/64), dim3(256), 0, stream>>>(
      (const char*)d_out, wgt, bg, (float*)d_out);
}

// Round 12
// 96.896 us; speedup vs baseline: 1.7534x; 1.0103x over previous
//
#include <hip/hip_runtime.h>
#include <stdint.h>

typedef short bf16x8 __attribute__((ext_vector_type(8)));
typedef unsigned short u16x8 __attribute__((ext_vector_type(8)));
typedef float f32x4 __attribute__((ext_vector_type(4)));
typedef float f32x8 __attribute__((ext_vector_type(8)));

constexpr int BT_TOT = 768;   // B*T
constexpr int M_N    = 512;   // nodes
constexpr int DD     = 64;    // Din = Dout
constexpr int WROW   = 72;    // W' row stride in route_mm

constexpr size_t ADJ_FRAG_B = (size_t)M_N * M_N * 2;          // 512 KB
constexpr size_t HWS_B      = (size_t)BT_TOT * M_N * DD * 2;  // 48 MB  (dense H')
constexpr size_t XTF_B      = (size_t)BT_TOT * M_N * DD * 2;  // 48 MB  (fb xtf)

__device__ __forceinline__ unsigned short f2bf(float f) {
  unsigned u = __builtin_bit_cast(unsigned, f);
  u += 0x7fffu + ((u >> 16) & 1u);          // RNE
  return (unsigned short)(u >> 16);
}
__device__ __forceinline__ unsigned pk2(float a, float b) {
  return (unsigned)f2bf(a) | ((unsigned)f2bf(b) << 16);
}

// ---- adj f32 -> bf16 MFMA-fragment layout (verified r11) ----
__global__ __launch_bounds__(256)
void prep_adj_frag(const float* __restrict__ adjg, unsigned short* __restrict__ wsadj) {
  int t  = blockIdx.x * 256 + threadIdx.x;   // granule id = m*64 + ko
  int m  = t >> 6, ko = t & 63;
  f32x8 a = *(const f32x8*)(adjg + (size_t)m * M_N + ko * 8);
  u16x8 r;
  #pragma unroll
  for (int j = 0; j < 8; ++j) r[j] = f2bf(a[j]);
  size_t g = (size_t)((m >> 4) * 16 + (ko >> 2)) * 64 + (ko & 3) * 16 + (m & 15);
  *(u16x8*)(wsadj + g * 8) = r;
}

// ---- gconv v12: fused transpose + GEMM. WG = 1 bt x 512 m, 512 thr ----
// Stage x[bt] once (coalesced + verified butterfly) into LDS in fragment-granule
// order, slot-XOR (d&15)^dt => conflict-free write AND linear read. One barrier,
// then pure MFMA: afr contiguous from adjF (L2), bfx linear from LDS.
// H' written DENSE to ws (128B rows) via LDS repack -> contiguous 1KB stores.
__global__ __launch_bounds__(512, 4)
void gconv_v12(const float* __restrict__ xg,
               const unsigned short* __restrict__ adjF,
               unsigned short* __restrict__ hws) {
  __shared__ __align__(16) char lds[65536];

  const int bt   = blockIdx.x;
  const int tid  = threadIdx.x;
  const int lane = tid & 63;
  const int w    = tid >> 6;            // wave 0..7: owns m in [w*64, w*64+64)
  const int l15  = lane & 15;
  const int gg   = lane >> 4;
  const int c4   = lane & 15;

  const float* xb = xg + (size_t)bt * (M_N * DD);

  // ---- stage all 512 n: 8 chunks x 2 sweeps; verified butterfly ----
  #pragma unroll 2
  for (int c = 0; c < 8; ++c) {
    unsigned gdw[4];
    #pragma unroll
    for (int sp = 0; sp < 2; ++sp) {
      const int n = c*64 + w*8 + sp*4 + gg;              // wave: 4 rows = 1KB contig
      f32x4 xv = *(const f32x4*)(xb + (size_t)n * DD + c4*4);
      unsigned u0 = pk2(xv.x, xv.y), u1 = pk2(xv.z, xv.w);
      unsigned t0 = __shfl_xor(u0, 32), t1 = __shfl_xor(u1, 32);
      unsigned v0 = (gg & 2) ? t1 : u0, v1 = (gg & 2) ? u1 : t0;
      unsigned s0 = __shfl_xor(v0, 16), s1 = __shfl_xor(v1, 16);
      unsigned F0 = (gg & 1) ? ((s0 >> 16) | (v0 & 0xFFFF0000u))
                             : ((v0 & 0xFFFFu) | (s0 << 16));
      unsigned F1 = (gg & 1) ? ((s1 >> 16) | (v1 & 0xFFFF0000u))
                             : ((v1 & 0xFFFFu) | (s1 << 16));
      gdw[sp*2] = F0; gdw[sp*2+1] = F1;
    }
    const int d  = c4*4 + gg;           // lane's final d (verified butterfly output)
    const int dt = d >> 4;
    const int o  = c*8 + w;             // n-octet; kl = o>>2, ggp = o&3
    uint4 val; val.x = gdw[0]; val.y = gdw[1]; val.z = gdw[2]; val.w = gdw[3];
    *(uint4*)(lds + ((((o >> 2)*4 + dt)*64 + (o & 3)*16 + ((d & 15) ^ dt)) << 4)) = val;
  }
  __syncthreads();                      // the only pre-compute barrier

  // ---- pure MFMA: wave = 64 m x 64 d, K = 512 ----
  f32x4 acc[4][4];
  #pragma unroll
  for (int mt = 0; mt < 4; ++mt)
    #pragma unroll
    for (int dt = 0; dt < 4; ++dt) acc[mt][dt] = f32x4{0.f,0.f,0.f,0.f};

  #pragma unroll 4
  for (int kl = 0; kl < 16; ++kl) {
    bf16x8 afr[4];
    #pragma unroll
    for (int mt = 0; mt < 4; ++mt)
      afr[mt] = __builtin_bit_cast(bf16x8, *(const u16x8*)(adjF
          + ((size_t)((w*4 + mt)*16 + kl)*64 + lane) * 8));
    bf16x8 bfx[4];
    #pragma unroll
    for (int dt = 0; dt < 4; ++dt)
      bfx[dt] = __builtin_bit_cast(bf16x8, *(const u16x8*)(lds
          + (((kl*4 + dt)*64 + gg*16 + (l15 ^ dt)) << 4)));
    #pragma unroll
    for (int mt = 0; mt < 4; ++mt)
      #pragma unroll
      for (int dt = 0; dt < 4; ++dt)
        acc[mt][dt] = __builtin_amdgcn_mfma_f32_16x16x32_bf16(
            afr[mt], bfx[dt], acc[mt][dt], 0,0,0);
  }

  // ---- epilogue: acc -> LDS [m][d] (xor-oct) -> dense H' stores ----
  __syncthreads();                      // all bfx reads done; reuse lds
  #pragma unroll
  for (int mt = 0; mt < 4; ++mt)
    #pragma unroll
    for (int dt = 0; dt < 4; ++dt)
      #pragma unroll
      for (int r = 0; r < 4; ++r) {
        const int m = w*64 + mt*16 + gg*4 + r;   // C row = (lane>>4)*4 + reg
        const int d = dt*16 + l15;
        const int q = d >> 3;
        *(unsigned short*)(lds + m*128 + (((q ^ (m & 7)) << 4)) + (d & 7)*2)
            = f2bf(acc[mt][dt][r]);
      }
  __syncthreads();
  char* hrow = (char*)(hws + (size_t)bt * (M_N * DD));
  #pragma unroll
  for (int i = 0; i < 8; ++i) {
    const int g = tid + i*512;          // granule 0..4095; m = g>>3, q = g&7
    const int m = g >> 3, q = g & 7;
    uint4 v = *(const uint4*)(lds + m*128 + ((q ^ (m & 7)) << 4));
    *(uint4*)(hrow + g*16) = v;         // = m*128 + q*16 : fully contiguous
  }
}

// ================= FALLBACK PATH (r10/r11 verified) =================

__global__ __launch_bounds__(256)
void prep_adj(const float* __restrict__ adjg, unsigned short* __restrict__ wsadj) {
  int i = (blockIdx.x * 256 + threadIdx.x) * 8;
  f32x8 a = *(const f32x8*)(adjg + i);
  u16x8 r;
  #pragma unroll
  for (int j = 0; j < 8; ++j) r[j] = f2bf(a[j]);
  *(u16x8*)(wsadj + i) = r;
}

__global__ __launch_bounds__(256, 4)
void prep_x_fb(const float* __restrict__ xg, char* __restrict__ xout) {
  __shared__ __align__(16) char lds[2][8192];
  const int wid  = blockIdx.x;
  const int bt   = wid >> 1, half = wid & 1;
  const int tid  = threadIdx.x, lane = tid & 63, wv = tid >> 6;
  const int gg   = lane >> 4, c4 = lane & 15;
  const float* xb = xg + (size_t)bt * (M_N * DD);
  f32x4 xv[4];
  auto load_c = [&](int c) {
    #pragma unroll
    for (int s = 0; s < 4; ++s)
      xv[s] = *(const f32x4*)(xb + (size_t)(c*64 + s*16 + wv*4 + gg) * DD + c4*4);
  };
  load_c(half*4);
  #pragma unroll
  for (int cc = 0; cc < 4; ++cc) {
    const int c = half*4 + cc;
    char* xt = &lds[cc & 1][0];
    { const int d = c4*4 + gg, g3d = (d & 7) ^ ((d >> 3) & 7);
      #pragma unroll
      for (int s = 0; s < 4; ++s) {
        const int n4 = s*4 + wv;
        unsigned u0 = pk2(xv[s].x, xv[s].y), u1 = pk2(xv[s].z, xv[s].w);
        unsigned t0 = __shfl_xor(u0, 32), t1 = __shfl_xor(u1, 32);
        unsigned v0 = (gg & 2) ? t1 : u0, v1 = (gg & 2) ? u1 : t0;
        unsigned s0 = __shfl_xor(v0, 16), s1 = __shfl_xor(v1, 16);
        unsigned F0 = (gg & 1) ? ((s0 >> 16) | (v0 & 0xFFFF0000u))
                               : ((v0 & 0xFFFFu) | (s0 << 16));
        unsigned F1 = (gg & 1) ? ((s1 >> 16) | (v1 & 0xFFFF0000u))
                               : ((v1 & 0xFFFFu) | (s1 << 16));
        uint2 o2; o2.x = F0; o2.y = F1;
        *(uint2*)(xt + d*128 + (((n4 >> 1) ^ g3d) * 16) + (n4 & 1)*8) = o2;
      }
    }
    if (cc < 3) load_c(c + 1);
    __syncthreads();
    #pragma unroll
    for (int h = 0; h < 2; ++h) {
      const int g = tid + h*256, d = g >> 3, o = g & 7;
      const int g3d = (d & 7) ^ ((d >> 3) & 7);
      u16x8 val = *(const u16x8*)(xt + d*128 + ((o ^ g3d) * 16));
      *(u16x8*)(xout + ((size_t)(bt*512 + 8*d + c)) * 256 + 128 + o*16) = val;
    }
  }
}

template<bool WS>
__global__ __launch_bounds__(256, 3)
void gconv_fb(const float* __restrict__ adjf,
              const unsigned short* __restrict__ adjb,
              char* __restrict__ dio) {
  const int wid  = blockIdx.x;
  const int xcd  = wid & 7, slot = wid >> 3;
  const int mb   = slot & 3;
  const int bt0  = ((slot >> 2) * 8 + xcd) * 2;
  const int tid  = threadIdx.x, lane = tid & 63, wv = tid >> 6;
  const int l15  = lane & 15, gg = lane >> 4;
  const int mrow = mb*128 + wv*32;
  f32x4 acc[2][2][4];
  #pragma unroll
  for (int bb = 0; bb < 2; ++bb)
    #pragma unroll
    for (int mt = 0; mt < 2; ++mt)
      #pragma unroll
      for (int dt = 0; dt < 4; ++dt) acc[bb][mt][dt] = f32x4{0.f,0.f,0.f,0.f};
  #pragma unroll 4
  for (int kl = 0; kl < 16; ++kl) {
    bf16x8 afr[2];
    #pragma unroll
    for (int mt = 0; mt < 2; ++mt) {
      const int m = mrow + mt*16 + l15;
      if (WS) {
        afr[mt] = __builtin_bit_cast(bf16x8,
            *(const u16x8*)(adjb + (size_t)m*M_N + kl*32 + gg*8));
      } else {
        f32x8 a = *(const f32x8*)(adjf + (size_t)m*M_N + kl*32 + gg*8);
        u16x8 r;
        #pragma unroll
        for (int j = 0; j < 8; ++j) r[j] = f2bf(a[j]);
        afr[mt] = __builtin_bit_cast(bf16x8, r);
      }
    }
    bf16x8 bfx[2][4];
    #pragma unroll
    for (int bb = 0; bb < 2; ++bb)
      #pragma unroll
      for (int dt = 0; dt < 4; ++dt) {
        const int d = dt*16 + l15;
        bfx[bb][dt] = __builtin_bit_cast(bf16x8, *(const u16x8*)(dio
            + ((size_t)((bt0+bb)*512 + 8*d + (kl >> 1))) * 256
            + 128 + (kl & 1)*64 + gg*16));
      }
    #pragma unroll
    for (int bb = 0; bb < 2; ++bb)
      #pragma unroll
      for (int mt = 0; mt < 2; ++mt)
        #pragma unroll
        for (int dt = 0; dt < 4; ++dt)
          acc[bb][mt][dt] = __builtin_amdgcn_mfma_f32_16x16x32_bf16(
              afr[mt], bfx[bb][dt], acc[bb][mt][dt], 0,0,0);
  }
  #pragma unroll
  for (int bb = 0; bb < 2; ++bb)
    #pragma unroll
    for (int mt = 0; mt < 2; ++mt)
      #pragma unroll
      for (int dt = 0; dt < 4; ++dt)
        #pragma unroll
        for (int r = 0; r < 4; ++r) {
          const int m = mrow + mt*16 + gg*4 + r, d = dt*16 + l15;
          *(unsigned short*)(dio + ((size_t)(bt0+bb)*M_N + m)*256 + 2*d)
              = f2bf(acc[bb][mt][dt][r]);
        }
}

// ---------------- route_mm (verified; hstride parameterizes H row bytes) ----------------
__global__ __launch_bounds__(256, 4)
void route_mm(const char* __restrict__ hin, int hstride,
              const float* __restrict__ wgt,
              const float* __restrict__ bias,
              float* __restrict__ outg) {
  __shared__ unsigned short wb[128 * WROW];
  const int m0    = blockIdx.x * 2;
  const int btblk = blockIdx.y * 64;
  const int tid   = threadIdx.x, lane = tid & 63, wv = tid >> 6;
  const int l15   = lane & 15, gg = lane >> 4;
  const int dp    = tid & 31, lo = tid >> 5;
  { const float* q = wgt + ((size_t)m0*64 + dp*2)*64 + lo*8;
    f32x8 w0 = *(const f32x8*)q;          f32x8 w1 = *(const f32x8*)(q+64);
    f32x8 w2 = *(const f32x8*)(q+4096);   f32x8 w3 = *(const f32x8*)(q+4160);
    #pragma unroll
    for (int e = 0; e < 8; ++e) {
      int lrow = lo*8 + e;
      *(unsigned*)(wb + lrow*WROW + dp*2)        = pk2(w0[e], w1[e]);
      *(unsigned*)(wb + (64 + lrow)*WROW + dp*2) = pk2(w2[e], w3[e]);
    }
  }
  __syncthreads();
  const int btw0 = btblk + wv*16;
  #pragma unroll
  for (int mm = 0; mm < 2; ++mm) {
    const int m = m0 + mm;
    bf16x8 afr[2];
    #pragma unroll
    for (int ks = 0; ks < 2; ++ks) {
      const char* hp = hin + ((size_t)(btw0 + l15)*M_N + m)*hstride + ks*64 + gg*16;
      afr[ks] = __builtin_bit_cast(bf16x8, *(const u16x8*)hp);
    }
    f32x4 acc[4];
    #pragma unroll
    for (int lt = 0; lt < 4; ++lt) acc[lt] = f32x4{0.f,0.f,0.f,0.f};
    #pragma unroll
    for (int lt = 0; lt < 4; ++lt)
      #pragma unroll
      for (int ks = 0; ks < 2; ++ks) {
        bf16x8 bfr = __builtin_bit_cast(bf16x8,
            *(const u16x8*)(wb + (mm*64 + lt*16 + l15)*WROW + ks*32 + gg*8));
        acc[lt] = __builtin_amdgcn_mfma_f32_16x16x32_bf16(afr[ks], bfr, acc[lt], 0,0,0);
      }
    #pragma unroll
    for (int lt = 0; lt < 4; ++lt) {
      float bv = bias[m*64 + lt*16 + l15];
      #pragma unroll
      for (int r = 0; r < 4; ++r) {
        size_t row = (size_t)(btw0 + gg*4 + r)*M_N + m;
        outg[row*64 + lt*16 + l15] = acc[lt][r] + bv;
      }
    }
  }
}

extern "C" void kernel_launch(void* const* d_in, const int* in_sizes, int n_in,
                              void* d_out, int out_size, void* d_ws, size_t ws_size,
                              hipStream_t stream) {
  const float* xg   = (const float*)d_in[0];
  const float* adjg = (const float*)d_in[1];
  const float* wgt  = (const float*)d_in[2];
  const float* bg   = (const float*)d_in[3];

  if (ws_size >= ADJ_FRAG_B + HWS_B) {
    unsigned short* adjF = (unsigned short*)d_ws;
    unsigned short* hws  = (unsigned short*)((char*)d_ws + ADJ_FRAG_B);
    prep_adj_frag<<<dim3(128), dim3(256), 0, stream>>>(adjg, adjF);
    gconv_v12<<<dim3(BT_TOT), dim3(512), 0, stream>>>(xg, adjF, hws);
    route_mm<<<dim3(M_N/2, BT_TOT/64), dim3(256), 0, stream>>>(
        (const char*)hws, 128, wgt, bg, (float*)d_out);
  } else {
    prep_x_fb<<<dim3(BT_TOT * 2), dim3(256), 0, stream>>>(xg, (char*)d_out);
    if (ws_size >= ADJ_FRAG_B) {
      unsigned short* wsadj = (unsigned short*)d_ws;
      prep_adj<<<dim3(M_N * M_N / (256 * 8)), dim3(256), 0, stream>>>(adjg, wsadj);
      gconv_fb<true><<<dim3(1536), dim3(256), 0, stream>>>(adjg, wsadj, (char*)d_out);
    } else {
      gconv_fb<false><<<dim3(1536), dim3(256), 0, stream>>>(adjg, nullptr, (char*)d_out);
    }
    route_mm<<<dim3(M_N/2, BT_TOT/64), dim3(256), 0, stream>>>(
        (const char*)d_out, 256, wgt, bg, (float*)d_out);
  }
}